// Round 2
// baseline (3516.484 us; speedup 1.0000x reference)
//
#include <hip/hip_runtime.h>
#include <stdint.h>

typedef __attribute__((ext_vector_type(8))) short bf16x8;
typedef __attribute__((ext_vector_type(4))) float f32x4;
typedef unsigned long long u64;

static constexpr int NB = 8192;    // batch
static constexpr int DD = 768;     // model dim (K)
static constexpr int FF = 32768;   // latent dim (N)
static constexpr int TK = 32;      // top-k
static constexpr int RUNC = 64;    // running candidate cap per row

__device__ __forceinline__ ushort f2bf(float f) {
    unsigned x = __float_as_uint(f);
    unsigned r = (x + 0x7FFFu + ((x >> 16) & 1u)) >> 16;
    return (ushort)r;
}

// ---------------- prep: x_bf16 = bf16(x - pre_bias) ----------------
__global__ __launch_bounds__(256) void prep_x_k(const float* __restrict__ x,
                                                const float* __restrict__ pb,
                                                ushort* __restrict__ x16) {
    const int n4 = NB * DD / 4;
    for (int i = blockIdx.x * 256 + threadIdx.x; i < n4; i += gridDim.x * 256) {
        float4 v = ((const float4*)x)[i];
        float4 p = ((const float4*)pb)[i % (DD / 4)];
        ushort4 o;
        o.x = f2bf(v.x - p.x); o.y = f2bf(v.y - p.y);
        o.z = f2bf(v.z - p.z); o.w = f2bf(v.w - p.w);
        ((ushort4*)x16)[i] = o;
    }
}

// ------------- prep: transpose W_enc [D,F] -> Wt [F,D] (bf16 + optional f32) -------------
__global__ __launch_bounds__(256) void prep_w_k(const float* __restrict__ W,
                                                ushort* __restrict__ Wt16,
                                                float* __restrict__ Wt32) {
    __shared__ float tile[32][33];
    int f0 = blockIdx.x * 32, d0 = blockIdx.y * 32;
    int tx = threadIdx.x & 31, ty = threadIdx.x >> 5;  // ty 0..7
#pragma unroll
    for (int q = 0; q < 4; q++) {
        int dl = ty + q * 8;
        tile[dl][tx] = W[(size_t)(d0 + dl) * FF + f0 + tx];
    }
    __syncthreads();
#pragma unroll
    for (int q = 0; q < 4; q++) {
        int fl = ty + q * 8;
        float v = tile[tx][fl];
        size_t o = (size_t)(f0 + fl) * DD + d0 + tx;
        Wt16[o] = f2bf(v);
        if (Wt32) Wt32[o] = v;
    }
}

// ---------------- bf16 MFMA GEMM (conservative: reg-staged, padded linear LDS) ----------------
// latc[b][f-f0] = bf16( x16[b,:] . Wt16[f,:] + lbias[f] ), for f in [f0, f0+Fcn)
// 128x128 tile, BK=64, 4 waves (2x2), each wave 64x64 via 4x4 frags of 16x16x32.
__global__ __launch_bounds__(256) void gemm_k(const ushort* __restrict__ A,
                                              const ushort* __restrict__ Bt,
                                              const float* __restrict__ lbias,
                                              ushort* __restrict__ latc,
                                              int f0, int Fcn) {
    constexpr int LDR = 144;  // 64 bf16 + 8 pad -> bank stride 4 (2-way, free)
    __shared__ __align__(16) char As[128 * LDR];
    __shared__ __align__(16) char Bs[128 * LDR];

    int ntil = Fcn >> 7;
    int nwg = 64 * ntil;            // multiple of 8
    int cpx = nwg >> 3;
    int bid = (int)blockIdx.x;
    int wg = (bid & 7) * cpx + (bid >> 3);   // bijective XCD swizzle
    int mt = wg / ntil, nt = wg % ntil;
    int m0 = mt << 7, n0l = nt << 7;

    int t = threadIdx.x, l = t & 63;
    int w = t >> 6, wm = w >> 1, wn = w & 1;

    int rs = t >> 3, cs = t & 7;    // staging: row rs (0..31 per issue), 16B slot cs
    const ushort* ga = A + (size_t)(m0 + rs) * DD + cs * 8;
    const ushort* gb = Bt + (size_t)(f0 + n0l + rs) * DD + cs * 8;
    char* wA = As + rs * LDR + cs * 16;
    char* wB = Bs + rs * LDR + cs * 16;

    f32x4 acc[4][4] = {};
    int k0b = (l >> 4) << 4;        // byte offset of lane's 8-elem k-group

    for (int kt = 0; kt < DD; kt += 64) {
        uint4 va[4], vb[4];
#pragma unroll
        for (int i = 0; i < 4; i++) {
            va[i] = *(const uint4*)(ga + kt + (size_t)(i * 32) * DD);
            vb[i] = *(const uint4*)(gb + kt + (size_t)(i * 32) * DD);
        }
        __syncthreads();            // previous tile fully consumed
#pragma unroll
        for (int i = 0; i < 4; i++) {
            *(uint4*)(wA + i * 32 * LDR) = va[i];
            *(uint4*)(wB + i * 32 * LDR) = vb[i];
        }
        __syncthreads();
#pragma unroll
        for (int ks = 0; ks < 2; ks++) {
            bf16x8 af[4], bfr[4];
#pragma unroll
            for (int i = 0; i < 4; i++) {
                int rA = (wm << 6) + (i << 4) + (l & 15);
                int rB = (wn << 6) + (i << 4) + (l & 15);
                af[i]  = *(const bf16x8*)(As + rA * LDR + (ks << 6) + k0b);
                bfr[i] = *(const bf16x8*)(Bs + rB * LDR + (ks << 6) + k0b);
            }
#pragma unroll
            for (int mi = 0; mi < 4; mi++)
#pragma unroll
                for (int ni = 0; ni < 4; ni++)
                    acc[mi][ni] = __builtin_amdgcn_mfma_f32_16x16x32_bf16(
                        af[mi], bfr[ni], acc[mi][ni], 0, 0, 0);
        }
    }
    // epilogue: C/D map col=lane&15, row=(lane>>4)*4+j
#pragma unroll
    for (int ni = 0; ni < 4; ni++) {
        int gcl = n0l + (wn << 6) + (ni << 4) + (l & 15);
        float lbv = lbias[f0 + gcl];
#pragma unroll
        for (int mi = 0; mi < 4; mi++) {
            int gr = m0 + (wm << 6) + (mi << 4) + ((l >> 4) << 2);
            f32x4 v = acc[mi][ni];
#pragma unroll
            for (int j = 0; j < 4; j++)
                latc[(size_t)(gr + j) * Fcn + gcl] = f2bf(v[j] + lbv);
        }
    }
}

// ---------------- per-chunk select (rank-48 by sortable bf16 key) + merge into running top-64 ----------------
__global__ __launch_bounds__(256) void selmerge_k(const ushort* __restrict__ latc,
                                                  int f0, int Fcn,
                                                  unsigned* __restrict__ runkey,
                                                  int* __restrict__ runidx,
                                                  int* __restrict__ runcnt,
                                                  int first) {
    int b = blockIdx.x, t = threadIdx.x;
    __shared__ ushort rowc[16384];
    __shared__ unsigned hist[256];
    __shared__ u64 srt[256];
    __shared__ int s_cb, s_cum, s_T, s_cnt;

    const ushort* g = latc + (size_t)b * Fcn;
    for (int i = t; i < Fcn; i += 256) {
        ushort u = g[i];
        rowc[i] = (u & 0x8000u) ? (ushort)(u ^ 0xFFFFu) : (ushort)(u | 0x8000u);
    }
    hist[t] = 0;
    __syncthreads();
    // coarse histogram (key >> 8)
    for (int i = t; i < Fcn; i += 256) atomicAdd(&hist[rowc[i] >> 8], 1u);
    __syncthreads();
    if (t == 0) {
        int cum = 0, cb = 0;
        for (int i = 255; i >= 0; i--) {
            if (cum + (int)hist[i] >= 48) { cb = i; break; }
            cum += (int)hist[i];
        }
        s_cb = cb; s_cum = cum;
    }
    __syncthreads();
    int cb = s_cb;
    hist[t] = 0;
    __syncthreads();
    // fine histogram (key & 0xFF) within coarse bin
    for (int i = t; i < Fcn; i += 256)
        if ((int)(rowc[i] >> 8) == cb) atomicAdd(&hist[rowc[i] & 0xFF], 1u);
    __syncthreads();
    if (t == 0) {
        int cum = s_cum, T = cb << 8;
        for (int fb = 255; fb >= 0; fb--) {
            if (cum + (int)hist[fb] >= 48) { T = (cb << 8) | fb; break; }
            cum += (int)hist[fb];
        }
        s_T = T;
    }
    // load running list, pad
    int rc = first ? 0 : runcnt[b];
    if (t < rc)
        srt[t] = ((u64)runkey[(size_t)b * RUNC + t] << 32) |
                 (u64)(0xFFFFFFFFu - (unsigned)runidx[(size_t)b * RUNC + t]);
    else
        srt[t] = 0;
    if (t == 0) s_cnt = rc;
    __syncthreads();
    unsigned T = (unsigned)s_T;
    for (int i = t; i < Fcn; i += 256) {
        if (rowc[i] >= T) {
            int p = atomicAdd(&s_cnt, 1);
            if (p < 256)
                srt[p] = ((u64)rowc[i] << 32) | (u64)(0xFFFFFFFFu - (unsigned)(f0 + i));
        }
    }
    __syncthreads();
    // bitonic sort 256 descending
    for (int k = 2; k <= 256; k <<= 1) {
        for (int j = k >> 1; j > 0; j >>= 1) {
            int ixj = t ^ j;
            if (ixj > t) {
                u64 a = srt[t], c2 = srt[ixj];
                bool sw = ((t & k) == 0) ? (a < c2) : (a > c2);
                if (sw) { srt[t] = c2; srt[ixj] = a; }
            }
            __syncthreads();
        }
    }
    int tot = s_cnt < 256 ? s_cnt : 256;
    int nc = tot < RUNC ? tot : RUNC;
    if (t < RUNC) {
        u64 v = srt[t];
        runkey[(size_t)b * RUNC + t] = (unsigned)(v >> 32);
        runidx[(size_t)b * RUNC + t] = (int)(0xFFFFFFFFu - (unsigned)(v & 0xFFFFFFFFu));
    }
    if (t == 0) runcnt[b] = nc;
}

// ---------------- refine: fp64 re-dot of candidates, exact top-32 ----------------
__global__ __launch_bounds__(256) void refine_k(const float* __restrict__ x,
                                                const float* __restrict__ pb,
                                                const float* __restrict__ We,
                                                const float* __restrict__ Wt32,
                                                const float* __restrict__ lb,
                                                const int* __restrict__ runidx,
                                                const int* __restrict__ runcnt,
                                                int use_t,
                                                int* __restrict__ sidx,
                                                float* __restrict__ sval) {
    int b = blockIdx.x, t = threadIdx.x, l = t & 63, w = t >> 6;
    __shared__ float xs[DD];
    __shared__ int ci[RUNC];
    __shared__ float cv[RUNC];
    for (int i = t; i < DD; i += 256) xs[i] = x[(size_t)b * DD + i] - pb[i];
    int c = runcnt[b]; if (c > RUNC) c = RUNC;
    if (t < RUNC) cv[t] = -1e30f;
    if (t < c) ci[t] = runidx[(size_t)b * RUNC + t];
    __syncthreads();
    for (int j = w; j < c; j += 4) {
        int f = ci[j];
        double s = 0.0;
        if (use_t) {
            const float* wr = Wt32 + (size_t)f * DD;
#pragma unroll
            for (int q = 0; q < 12; q++)
                s = fma((double)wr[l + 64 * q], (double)xs[l + 64 * q], s);
        } else {
#pragma unroll
            for (int q = 0; q < 12; q++)
                s = fma((double)We[(size_t)(l + 64 * q) * FF + f], (double)xs[l + 64 * q], s);
        }
#pragma unroll
        for (int o = 32; o >= 1; o >>= 1) s += __shfl_down(s, o);
        if (l == 0) cv[j] = (float)(s + (double)lb[f]);
    }
    __syncthreads();
    if (w == 0) {
        float v0 = cv[l];
        int i0 = (l < c) ? ci[l] : 0x7FFFFFFF;
        for (int sel = 0; sel < TK; sel++) {
            float bv = v0; int bi = i0;
#pragma unroll
            for (int o = 32; o >= 1; o >>= 1) {
                float ov = __shfl_xor(bv, o);
                int oi = __shfl_xor(bi, o);
                if (ov > bv || (ov == bv && oi < bi)) { bv = ov; bi = oi; }
            }
            if (i0 == bi) v0 = -1e30f;  // remove winner
            if (l == 0) {
                sidx[(size_t)b * TK + sel] = bi;
                sval[(size_t)b * TK + sel] = bv > 0.f ? bv : 0.f;  // relu
            }
        }
    }
}

// ---------------- decode: recons = sum_j val_j * W_dec[idx_j,:] + pre_bias ----------------
__global__ __launch_bounds__(192) void decode_k(const float* __restrict__ sval,
                                                const int* __restrict__ sidx,
                                                const float* __restrict__ Wd,
                                                const float* __restrict__ pb,
                                                float* __restrict__ out) {
    int b = blockIdx.x, t = threadIdx.x;
    __shared__ float sv[TK];
    __shared__ int si[TK];
    if (t < TK) { sv[t] = sval[(size_t)b * TK + t]; si[t] = sidx[(size_t)b * TK + t]; }
    __syncthreads();
    float4 acc = ((const float4*)pb)[t];
#pragma unroll 4
    for (int j = 0; j < TK; j++) {
        float v = sv[j];
        float4 wv = ((const float4*)(Wd + (size_t)si[j] * DD))[t];
        acc.x += v * wv.x; acc.y += v * wv.y;
        acc.z += v * wv.z; acc.w += v * wv.w;
    }
    ((float4*)out)[(size_t)b * (DD / 4) + t] = acc;
}

extern "C" void kernel_launch(void* const* d_in, const int* in_sizes, int n_in,
                              void* d_out, int out_size, void* d_ws, size_t ws_size,
                              hipStream_t stream) {
    const float* x  = (const float*)d_in[0];
    const float* pb = (const float*)d_in[1];
    const float* We = (const float*)d_in[2];
    const float* lb = (const float*)d_in[3];
    const float* Wd = (const float*)d_in[4];
    float* out = (float*)d_out;
    char* ws = (char*)d_ws;
    (void)in_sizes; (void)n_in; (void)out_size;

    const size_t SZ_X16  = (size_t)NB * DD * 2;       // 12.6 MB
    const size_t SZ_WT16 = (size_t)FF * DD * 2;       // 50.3 MB
    const size_t SZ_WT32 = (size_t)FF * DD * 4;       // 100.7 MB
    const size_t SZ_RKEY = (size_t)NB * RUNC * 4;     // 2.1 MB
    const size_t SZ_RIDX = (size_t)NB * RUNC * 4;     // 2.1 MB
    const size_t SZ_RCNT = (size_t)NB * 4;
    const size_t SZ_SIDX = (size_t)NB * TK * 4;       // 1 MB
    const size_t SZ_SVAL = (size_t)NB * TK * 4;       // 1 MB

    size_t fixed = SZ_X16 + SZ_WT16 + SZ_RKEY + SZ_RIDX + SZ_RCNT + SZ_SIDX + SZ_SVAL;
    int use_t = (ws_size >= fixed + SZ_WT32 + (size_t)NB * 512 * 2) ? 1 : 0;
    size_t base = fixed + (use_t ? SZ_WT32 : 0);
    int Fc = 16384;
    while (Fc > 256 && base + (size_t)NB * Fc * 2 > ws_size) Fc >>= 1;

    size_t off = 0;
    ushort* x16   = (ushort*)(ws + off); off += SZ_X16;
    ushort* Wt16  = (ushort*)(ws + off); off += SZ_WT16;
    float*  Wt32  = nullptr;
    if (use_t) { Wt32 = (float*)(ws + off); off += SZ_WT32; }
    unsigned* rkey = (unsigned*)(ws + off); off += SZ_RKEY;
    int* ridx     = (int*)(ws + off); off += SZ_RIDX;
    int* rcnt     = (int*)(ws + off); off += SZ_RCNT;
    int* sidx     = (int*)(ws + off); off += SZ_SIDX;
    float* sval   = (float*)(ws + off); off += SZ_SVAL;
    ushort* latc  = (ushort*)(ws + off);

    prep_x_k<<<2048, 256, 0, stream>>>(x, pb, x16);
    prep_w_k<<<dim3(FF / 32, DD / 32), 256, 0, stream>>>(We, Wt16, Wt32);

    int nch = FF / Fc;
    for (int c = 0; c < nch; ++c) {
        gemm_k<<<64 * (Fc / 128), 256, 0, stream>>>(x16, Wt16, lb, latc, c * Fc, Fc);
        selmerge_k<<<NB, 256, 0, stream>>>(latc, c * Fc, Fc, rkey, ridx, rcnt, c == 0);
    }
    refine_k<<<NB, 256, 0, stream>>>(x, pb, We, Wt32, lb, ridx, rcnt, use_t, sidx, sval);
    decode_k<<<NB, 192, 0, stream>>>(sval, sidx, Wd, pb, out);
}

// Round 3
// 2180.617 us; speedup vs baseline: 1.6126x; 1.6126x over previous
//
#include <hip/hip_runtime.h>
#include <stdint.h>

#define GAS __attribute__((address_space(1)))
#define LAS __attribute__((address_space(3)))

typedef __attribute__((ext_vector_type(8))) short bf16x8;
typedef __attribute__((ext_vector_type(4))) float f32x4;
typedef unsigned long long u64;

static constexpr int NB = 8192;    // batch
static constexpr int DD = 768;     // model dim (K)
static constexpr int FF = 32768;   // latent dim (N)
static constexpr int TK = 32;      // top-k
static constexpr int RUNC = 64;    // running candidate cap per row

__device__ __forceinline__ ushort f2bf(float f) {
    unsigned x = __float_as_uint(f);
    unsigned r = (x + 0x7FFFu + ((x >> 16) & 1u)) >> 16;
    return (ushort)r;
}

__device__ __forceinline__ void gload_lds16(const void* g, void* l) {
    __builtin_amdgcn_global_load_lds((const GAS unsigned int*)g,
                                     (LAS unsigned int*)l, 16, 0, 0);
}

// ---------------- prep: x_bf16 = bf16(x - pre_bias) ----------------
__global__ __launch_bounds__(256) void prep_x_k(const float* __restrict__ x,
                                                const float* __restrict__ pb,
                                                ushort* __restrict__ x16) {
    const int n4 = NB * DD / 4;
    for (int i = blockIdx.x * 256 + threadIdx.x; i < n4; i += gridDim.x * 256) {
        float4 v = ((const float4*)x)[i];
        float4 p = ((const float4*)pb)[i % (DD / 4)];
        ushort4 o;
        o.x = f2bf(v.x - p.x); o.y = f2bf(v.y - p.y);
        o.z = f2bf(v.z - p.z); o.w = f2bf(v.w - p.w);
        ((ushort4*)x16)[i] = o;
    }
}

// ------------- prep: transpose W_enc [D,F] -> Wt [F,D] (bf16 + optional f32) -------------
__global__ __launch_bounds__(256) void prep_w_k(const float* __restrict__ W,
                                                ushort* __restrict__ Wt16,
                                                float* __restrict__ Wt32) {
    __shared__ float tile[32][33];
    int f0 = blockIdx.x * 32, d0 = blockIdx.y * 32;
    int tx = threadIdx.x & 31, ty = threadIdx.x >> 5;  // ty 0..7
#pragma unroll
    for (int q = 0; q < 4; q++) {
        int dl = ty + q * 8;
        tile[dl][tx] = W[(size_t)(d0 + dl) * FF + f0 + tx];
    }
    __syncthreads();
#pragma unroll
    for (int q = 0; q < 4; q++) {
        int fl = ty + q * 8;
        float v = tile[tx][fl];
        size_t o = (size_t)(f0 + fl) * DD + d0 + tx;
        Wt16[o] = f2bf(v);
        if (Wt32) Wt32[o] = v;
    }
}

// ---------------- bf16 MFMA GEMM (m97 structure: global_load_lds 16B, linear LDS) ----------------
// latc[b][f-f0] = bf16( x16[b,:] . Wt16[f,:] + lbias[f] ), for f in [f0, f0+Fcn)
// 128x128 tile, BK=64, 4 waves (2x2), each wave 64x64 via 4x4 frags of 16x16x32.
// Epilogue staged through LDS for full-sector vectorized global stores.
__global__ __launch_bounds__(256) void gemm_k(const ushort* __restrict__ A,
                                              const ushort* __restrict__ Bt,
                                              const float* __restrict__ lbias,
                                              ushort* __restrict__ latc,
                                              int f0, int Fcn) {
    __shared__ __align__(16) char smem[34816];   // As 16K + Bs 16K; reused as Cs 34K
    char* As = smem;
    char* Bs = smem + 16384;

    int ntil = Fcn >> 7;
    int nwg = 64 * ntil;            // multiple of 8
    int cpx = nwg >> 3;
    int bid = (int)blockIdx.x;
    int wg = (bid & 7) * cpx + (bid >> 3);   // bijective XCD swizzle (nwg%8==0)
    int mt = wg / ntil, nt = wg % ntil;
    int m0 = mt << 7, n0l = nt << 7;

    int t = threadIdx.x, l = t & 63;
    int w = t >> 6, wm = w >> 1, wn = w & 1;

    // staging: issue i covers rows i*32..i*32+31; thread t -> row t>>3, 16B slot t&7
    int rs = t >> 3, cs = t & 7;
    const ushort* ga = A + (size_t)(m0 + rs) * DD + cs * 8;
    const ushort* gb = Bt + (size_t)(f0 + n0l + rs) * DD + cs * 8;
    char* lA = As + t * 16;
    char* lB = Bs + t * 16;

    f32x4 acc[4][4] = {};
    int k0b = (l >> 4) << 4;        // byte offset of lane's 8-elem k-group

    for (int kt = 0; kt < DD; kt += 64) {
#pragma unroll
        for (int i = 0; i < 4; i++) {
            gload_lds16(ga + kt + (size_t)(i * 32) * DD, lA + i * 4096);
            gload_lds16(gb + kt + (size_t)(i * 32) * DD, lB + i * 4096);
        }
        asm volatile("s_waitcnt vmcnt(0)" ::: "memory");
        __syncthreads();
#pragma unroll
        for (int ks = 0; ks < 2; ks++) {
            bf16x8 af[4], bfr[4];
#pragma unroll
            for (int i = 0; i < 4; i++) {
                int rA = (wm << 6) + (i << 4) + (l & 15);
                int rB = (wn << 6) + (i << 4) + (l & 15);
                af[i]  = *(const bf16x8*)(As + rA * 128 + (ks << 6) + k0b);
                bfr[i] = *(const bf16x8*)(Bs + rB * 128 + (ks << 6) + k0b);
            }
#pragma unroll
            for (int mi = 0; mi < 4; mi++)
#pragma unroll
                for (int ni = 0; ni < 4; ni++)
                    acc[mi][ni] = __builtin_amdgcn_mfma_f32_16x16x32_bf16(
                        af[mi], bfr[ni], acc[mi][ni], 0, 0, 0);
        }
        __syncthreads();
    }

    // ---- epilogue: C/D map col=lane&15, row=(lane>>4)*4+j; stage to LDS, flush vectorized ----
    constexpr int LDC = 136;  // ushorts per row (+8 pad)
    ushort* Cs = (ushort*)smem;
#pragma unroll
    for (int ni = 0; ni < 4; ni++) {
        int lc = (wn << 6) + (ni << 4) + (l & 15);
        float lbv = lbias[f0 + n0l + lc];
#pragma unroll
        for (int mi = 0; mi < 4; mi++) {
            int lr = (wm << 6) + (mi << 4) + ((l >> 4) << 2);
            f32x4 v = acc[mi][ni];
#pragma unroll
            for (int j = 0; j < 4; j++)
                Cs[(lr + j) * LDC + lc] = f2bf(v[j] + lbv);
        }
    }
    __syncthreads();
    // flush: 8 lanes x 16B = 128B contiguous per row-group, full sectors
    {
        int r0 = t >> 3, c0 = (t & 7) * 8;
#pragma unroll
        for (int it = 0; it < 4; it++) {
#pragma unroll
            for (int c2 = 0; c2 < 2; c2++) {
                int r = r0 + it * 32, c = c0 + c2 * 64;
                *(uint4*)(latc + (size_t)(m0 + r) * Fcn + n0l + c) =
                    *(const uint4*)(Cs + r * LDC + c);
            }
        }
    }
}

// ---------------- per-chunk select (rank-48 by sortable bf16 key) + merge into running top-64 ----------------
__global__ __launch_bounds__(256) void selmerge_k(const ushort* __restrict__ latc,
                                                  int f0, int Fcn,
                                                  unsigned* __restrict__ runkey,
                                                  int* __restrict__ runidx,
                                                  int* __restrict__ runcnt,
                                                  int first) {
    int b = blockIdx.x, t = threadIdx.x;
    __shared__ ushort rowc[16384];
    __shared__ unsigned hist[256];
    __shared__ u64 srt[256];
    __shared__ int s_cb, s_cum, s_T, s_cnt;

    const ushort* g = latc + (size_t)b * Fcn;
    for (int i = t; i < Fcn; i += 256) {
        ushort u = g[i];
        rowc[i] = (u & 0x8000u) ? (ushort)(u ^ 0xFFFFu) : (ushort)(u | 0x8000u);
    }
    hist[t] = 0;
    __syncthreads();
    for (int i = t; i < Fcn; i += 256) atomicAdd(&hist[rowc[i] >> 8], 1u);
    __syncthreads();
    if (t == 0) {
        int cum = 0, cb = 0;
        for (int i = 255; i >= 0; i--) {
            if (cum + (int)hist[i] >= 48) { cb = i; break; }
            cum += (int)hist[i];
        }
        s_cb = cb; s_cum = cum;
    }
    __syncthreads();
    int cb = s_cb;
    hist[t] = 0;
    __syncthreads();
    for (int i = t; i < Fcn; i += 256)
        if ((int)(rowc[i] >> 8) == cb) atomicAdd(&hist[rowc[i] & 0xFF], 1u);
    __syncthreads();
    if (t == 0) {
        int cum = s_cum, T = cb << 8;
        for (int fb = 255; fb >= 0; fb--) {
            if (cum + (int)hist[fb] >= 48) { T = (cb << 8) | fb; break; }
            cum += (int)hist[fb];
        }
        s_T = T;
    }
    int rc = first ? 0 : runcnt[b];
    if (t < rc)
        srt[t] = ((u64)runkey[(size_t)b * RUNC + t] << 32) |
                 (u64)(0xFFFFFFFFu - (unsigned)runidx[(size_t)b * RUNC + t]);
    else
        srt[t] = 0;
    if (t == 0) s_cnt = rc;
    __syncthreads();
    unsigned T = (unsigned)s_T;
    for (int i = t; i < Fcn; i += 256) {
        if (rowc[i] >= T) {
            int p = atomicAdd(&s_cnt, 1);
            if (p < 256)
                srt[p] = ((u64)rowc[i] << 32) | (u64)(0xFFFFFFFFu - (unsigned)(f0 + i));
        }
    }
    __syncthreads();
    for (int k = 2; k <= 256; k <<= 1) {
        for (int j = k >> 1; j > 0; j >>= 1) {
            int ixj = t ^ j;
            if (ixj > t) {
                u64 a = srt[t], c2 = srt[ixj];
                bool sw = ((t & k) == 0) ? (a < c2) : (a > c2);
                if (sw) { srt[t] = c2; srt[ixj] = a; }
            }
            __syncthreads();
        }
    }
    int tot = s_cnt < 256 ? s_cnt : 256;
    int nc = tot < RUNC ? tot : RUNC;
    if (t < RUNC) {
        u64 v = srt[t];
        runkey[(size_t)b * RUNC + t] = (unsigned)(v >> 32);
        runidx[(size_t)b * RUNC + t] = (int)(0xFFFFFFFFu - (unsigned)(v & 0xFFFFFFFFu));
    }
    if (t == 0) runcnt[b] = nc;
}

// ---------------- refine: fp64 re-dot of candidates, exact top-32 ----------------
__global__ __launch_bounds__(256) void refine_k(const float* __restrict__ x,
                                                const float* __restrict__ pb,
                                                const float* __restrict__ We,
                                                const float* __restrict__ Wt32,
                                                const float* __restrict__ lb,
                                                const int* __restrict__ runidx,
                                                const int* __restrict__ runcnt,
                                                int use_t,
                                                int* __restrict__ sidx,
                                                float* __restrict__ sval) {
    int b = blockIdx.x, t = threadIdx.x, l = t & 63, w = t >> 6;
    __shared__ float xs[DD];
    __shared__ int ci[RUNC];
    __shared__ float cv[RUNC];
    for (int i = t; i < DD; i += 256) xs[i] = x[(size_t)b * DD + i] - pb[i];
    int c = runcnt[b]; if (c > RUNC) c = RUNC;
    if (t < RUNC) cv[t] = -1e30f;
    if (t < c) ci[t] = runidx[(size_t)b * RUNC + t];
    __syncthreads();
    for (int j = w; j < c; j += 4) {
        int f = ci[j];
        double s = 0.0;
        if (use_t) {
            const float* wr = Wt32 + (size_t)f * DD;
#pragma unroll
            for (int q = 0; q < 12; q++)
                s = fma((double)wr[l + 64 * q], (double)xs[l + 64 * q], s);
        } else {
#pragma unroll
            for (int q = 0; q < 12; q++)
                s = fma((double)We[(size_t)(l + 64 * q) * FF + f], (double)xs[l + 64 * q], s);
        }
#pragma unroll
        for (int o = 32; o >= 1; o >>= 1) s += __shfl_down(s, o);
        if (l == 0) cv[j] = (float)(s + (double)lb[f]);
    }
    __syncthreads();
    if (w == 0) {
        float v0 = cv[l];
        int i0 = (l < c) ? ci[l] : 0x7FFFFFFF;
        for (int sel = 0; sel < TK; sel++) {
            float bv = v0; int bi = i0;
#pragma unroll
            for (int o = 32; o >= 1; o >>= 1) {
                float ov = __shfl_xor(bv, o);
                int oi = __shfl_xor(bi, o);
                if (ov > bv || (ov == bv && oi < bi)) { bv = ov; bi = oi; }
            }
            if (i0 == bi) v0 = -1e30f;  // remove winner
            if (l == 0) {
                sidx[(size_t)b * TK + sel] = bi;
                sval[(size_t)b * TK + sel] = bv > 0.f ? bv : 0.f;  // relu
            }
        }
    }
}

// ---------------- decode: recons = sum_j val_j * W_dec[idx_j,:] + pre_bias ----------------
__global__ __launch_bounds__(192) void decode_k(const float* __restrict__ sval,
                                                const int* __restrict__ sidx,
                                                const float* __restrict__ Wd,
                                                const float* __restrict__ pb,
                                                float* __restrict__ out) {
    int b = blockIdx.x, t = threadIdx.x;
    __shared__ float sv[TK];
    __shared__ int si[TK];
    if (t < TK) { sv[t] = sval[(size_t)b * TK + t]; si[t] = sidx[(size_t)b * TK + t]; }
    __syncthreads();
    float4 acc = ((const float4*)pb)[t];
#pragma unroll 4
    for (int j = 0; j < TK; j++) {
        float v = sv[j];
        float4 wv = ((const float4*)(Wd + (size_t)si[j] * DD))[t];
        acc.x += v * wv.x; acc.y += v * wv.y;
        acc.z += v * wv.z; acc.w += v * wv.w;
    }
    ((float4*)out)[(size_t)b * (DD / 4) + t] = acc;
}

extern "C" void kernel_launch(void* const* d_in, const int* in_sizes, int n_in,
                              void* d_out, int out_size, void* d_ws, size_t ws_size,
                              hipStream_t stream) {
    const float* x  = (const float*)d_in[0];
    const float* pb = (const float*)d_in[1];
    const float* We = (const float*)d_in[2];
    const float* lb = (const float*)d_in[3];
    const float* Wd = (const float*)d_in[4];
    float* out = (float*)d_out;
    char* ws = (char*)d_ws;
    (void)in_sizes; (void)n_in; (void)out_size;

    const size_t SZ_X16  = (size_t)NB * DD * 2;       // 12.6 MB
    const size_t SZ_WT16 = (size_t)FF * DD * 2;       // 50.3 MB
    const size_t SZ_WT32 = (size_t)FF * DD * 4;       // 100.7 MB
    const size_t SZ_RKEY = (size_t)NB * RUNC * 4;
    const size_t SZ_RIDX = (size_t)NB * RUNC * 4;
    const size_t SZ_RCNT = (size_t)NB * 4;
    const size_t SZ_SIDX = (size_t)NB * TK * 4;
    const size_t SZ_SVAL = (size_t)NB * TK * 4;

    size_t fixed = SZ_X16 + SZ_WT16 + SZ_RKEY + SZ_RIDX + SZ_RCNT + SZ_SIDX + SZ_SVAL;
    int use_t = (ws_size >= fixed + SZ_WT32 + (size_t)NB * 512 * 2) ? 1 : 0;
    size_t base = fixed + (use_t ? SZ_WT32 : 0);
    int Fc = 16384;
    while (Fc > 256 && base + (size_t)NB * Fc * 2 > ws_size) Fc >>= 1;

    size_t off = 0;
    ushort* x16   = (ushort*)(ws + off); off += SZ_X16;
    ushort* Wt16  = (ushort*)(ws + off); off += SZ_WT16;
    float*  Wt32  = nullptr;
    if (use_t) { Wt32 = (float*)(ws + off); off += SZ_WT32; }
    unsigned* rkey = (unsigned*)(ws + off); off += SZ_RKEY;
    int* ridx     = (int*)(ws + off); off += SZ_RIDX;
    int* rcnt     = (int*)(ws + off); off += SZ_RCNT;
    int* sidx     = (int*)(ws + off); off += SZ_SIDX;
    float* sval   = (float*)(ws + off); off += SZ_SVAL;
    ushort* latc  = (ushort*)(ws + off);

    prep_x_k<<<2048, 256, 0, stream>>>(x, pb, x16);
    prep_w_k<<<dim3(FF / 32, DD / 32), 256, 0, stream>>>(We, Wt16, Wt32);

    int nch = FF / Fc;
    for (int c = 0; c < nch; ++c) {
        gemm_k<<<64 * (Fc / 128), 256, 0, stream>>>(x16, Wt16, lb, latc, c * Fc, Fc);
        selmerge_k<<<NB, 256, 0, stream>>>(latc, c * Fc, Fc, rkey, ridx, rcnt, c == 0);
    }
    refine_k<<<NB, 256, 0, stream>>>(x, pb, We, Wt32, lb, ridx, rcnt, use_t, sidx, sval);
    decode_k<<<NB, 192, 0, stream>>>(sval, sidx, Wd, pb, out);
}